// Round 3
// baseline (265.447 us; speedup 1.0000x reference)
//
#include <hip/hip_runtime.h>

#define IMG_H 512
#define IMG_W 512
#define RPB 16            // rows per block
#define NLEV 256
#define NB 32             // batch
#define NC 3              // channels
#define NHIST (NB * NC * NLEV)   // 24576 floats

// Histogram lives in module-scope device memory: no dependence on ws_size.
__device__ float g_hist[NHIST];

struct F3 { float r, g, b; };

__device__ __forceinline__ float wrap1(float v) {
    return fmodf(v + 1.0f, 2.0f) - 1.0f;   // truncated fmod == jnp.fmod
}

// Color transform + fmod wrap for pixel (b,h,w). 3 global loads.
__device__ __forceinline__ F3 transform(const float* __restrict__ x,
                                        const float* __restrict__ p,
                                        int b, int h, int w) {
    int base = ((b * 3) * IMG_H + h) * IMG_W + w;
    float r0 = x[base];
    float g0 = x[base + IMG_H * IMG_W];
    float b0 = x[base + 2 * IMG_H * IMG_W];
    float r1 = r0 + (p[0] * g0 + p[1] * b0);
    float g1 = g0 + (p[2] * r1 + p[3] * b0);
    float b1 = b0 + (p[4] * r1 + p[5] * g1);
    float r2 = r1 + (p[6] * g1 + p[7] * b1);
    float g2 = g1 + (p[8] * r2 + p[9] * b1);
    float b2 = b1 + (p[10] * r2 + p[11] * g2);
    return F3{wrap1(r2), wrap1(g2), wrap1(b2)};
}

// Residual -> 2 histogram adds. JAX semantics: negative indices wrap (+256)
// BEFORE the bounds check; only then are OOB indices dropped (mode='drop').
__device__ __forceinline__ void accum(float y, float n, float w, float nw,
                                      float* __restrict__ h) {
    float lo = fminf(n, w), hi = fmaxf(n, w);
    float pred = fminf(fmaxf(n + w - nw, lo), hi);
    float res = y - pred;
    float xs = (res + 1.0f) * 127.5f;      // (nlevels-1)/2
    float f = floorf(xs);
    float frac = xs - f;
    int i0 = (int)f;
    int j0 = (i0 < 0) ? i0 + NLEV : i0;    // JAX negative-index wrap
    if ((unsigned)j0 < (unsigned)NLEV) atomicAdd(&h[j0], 1.0f - frac);
    int i1 = i0 + 1;
    int j1 = (i1 < 0) ? i1 + NLEV : i1;
    if ((unsigned)j1 < (unsigned)NLEV) atomicAdd(&h[j1], frac);
}

__global__ void zero_hist() {
    int i = blockIdx.x * 256 + threadIdx.x;
    if (i < NHIST) g_hist[i] = 0.0f;
}

__global__ __launch_bounds__(512) void hist_kernel(const float* __restrict__ x,
                                                   const float* __restrict__ params) {
    // per-wave sub-histograms: 8 waves x 3 channels x 256 bins = 24 KiB
    __shared__ float lh[8][NC][NLEV];
    const int tid = threadIdx.x;
    const int b = blockIdx.x;
    const int r0 = blockIdx.y * RPB;
    const int wv = tid >> 6;
    const int col = tid;   // 0..511, one column per thread

    float* lp = &lh[0][0][0];
    for (int i = tid; i < 8 * NC * NLEV; i += 512) lp[i] = 0.0f;
    __syncthreads();

    float p[12];
#pragma unroll
    for (int i = 0; i < 12; ++i) p[i] = params[i];

    // north / northwest carried in registers across rows (same thread, no shfl).
    F3 n = {0.f, 0.f, 0.f}, nw = {0.f, 0.f, 0.f};
    if (r0 > 0) {
        n = transform(x, p, b, r0 - 1, col);
        if (col > 0) nw = transform(x, p, b, r0 - 1, col - 1);
    }

    float* h0 = &lh[wv][0][0];
    float* h1 = &lh[wv][1][0];
    float* h2 = &lh[wv][2][0];

    for (int h = r0; h < r0 + RPB; ++h) {
        F3 cur = transform(x, p, b, h, col);
        F3 wst = {0.f, 0.f, 0.f};
        if (col > 0) wst = transform(x, p, b, h, col - 1);  // direct load, no shfl
        accum(cur.r, n.r, wst.r, nw.r, h0);
        accum(cur.g, n.g, wst.g, nw.g, h1);
        accum(cur.b, n.b, wst.b, nw.b, h2);
        n = cur;
        nw = wst;
    }
    __syncthreads();

    // flush: sum the 8 sub-histograms, one global atomic per bin
    for (int i = tid; i < NC * NLEV; i += 512) {
        int c = i >> 8;
        int bin = i & 255;
        float s = 0.0f;
#pragma unroll
        for (int w2 = 0; w2 < 8; ++w2) s += lh[w2][c][bin];
        atomicAdd(&g_hist[(b * NC + c) * NLEV + bin], s);
    }
}

__global__ void entropy_kernel(float* __restrict__ out) {
    const float inv_hw = 1.0f / (float)(IMG_H * IMG_W);
    float acc = 0.0f;
    for (int i = threadIdx.x; i < NHIST; i += 256) {
        float pr = g_hist[i] * inv_hw;
        if (pr > 0.0f) acc -= pr * log2f(pr);
    }
#pragma unroll
    for (int o = 32; o > 0; o >>= 1) acc += __shfl_down(acc, o);
    __shared__ float red[4];
    int wv = threadIdx.x >> 6;
    int lane = threadIdx.x & 63;
    if (lane == 0) red[wv] = acc;
    __syncthreads();
    if (threadIdx.x == 0) {
        float t = red[0] + red[1] + red[2] + red[3];
        out[0] = t * (1.0f / (float)(NB * NC) / 8.0f);  // mean over 96 rows, /nbits
    }
}

extern "C" void kernel_launch(void* const* d_in, const int* in_sizes, int n_in,
                              void* d_out, int out_size, void* d_ws, size_t ws_size,
                              hipStream_t stream) {
    const float* x = (const float*)d_in[0];
    const float* params = (const float*)d_in[1];
    float* out = (float*)d_out;

    zero_hist<<<(NHIST + 255) / 256, 256, 0, stream>>>();
    dim3 grid(NB, IMG_H / RPB);   // 32 x 32
    hist_kernel<<<grid, 512, 0, stream>>>(x, params);
    entropy_kernel<<<1, 256, 0, stream>>>(out);
}

// Round 4
// 250.170 us; speedup vs baseline: 1.0611x; 1.0611x over previous
//
#include <hip/hip_runtime.h>

#define IMG_H 512
#define IMG_W 512
#define RPB 16            // rows per block
#define NLEV 256
#define NB 32             // batch
#define NC 3              // channels
#define NHIST (NB * NC * NLEV)   // 24576 floats

__device__ float g_hist[NHIST];

struct F3 { float r, g, b; };

// fmodf(v+1, 2) - 1, branch-free. Exact for |v+1| < 2^23:
// fmod(a,2) = a - 2*trunc(a/2); a*0.5f is exact, trunc exact, and
// a - 2t is a multiple of ulp(a) with smaller magnitude -> exact.
__device__ __forceinline__ float wrap1(float v) {
    float a = v + 1.0f;
    return a - 2.0f * truncf(0.5f * a) - 1.0f;
}

// Color transform + wrap for pixel (b,h,w). 3 global loads.
__device__ __forceinline__ F3 transform(const float* __restrict__ x,
                                        const float* __restrict__ p,
                                        int b, int h, int w) {
    int base = ((b * 3) * IMG_H + h) * IMG_W + w;
    float r0 = x[base];
    float g0 = x[base + IMG_H * IMG_W];
    float b0 = x[base + 2 * IMG_H * IMG_W];
    float r1 = r0 + (p[0] * g0 + p[1] * b0);
    float g1 = g0 + (p[2] * r1 + p[3] * b0);
    float b1 = b0 + (p[4] * r1 + p[5] * g1);
    float r2 = r1 + (p[6] * g1 + p[7] * b1);
    float g2 = g1 + (p[8] * r2 + p[9] * b1);
    float b2 = b1 + (p[10] * r2 + p[11] * g2);
    return F3{wrap1(r2), wrap1(g2), wrap1(b2)};
}

// Residual -> 2 histogram adds. JAX semantics: negative indices wrap (+256)
// BEFORE the bounds check; only then are OOB indices dropped (mode='drop').
__device__ __forceinline__ void accum(float y, float n, float w, float nw,
                                      float* __restrict__ h) {
    float lo = fminf(n, w), hi = fmaxf(n, w);
    float pred = fminf(fmaxf(n + w - nw, lo), hi);
    float res = y - pred;
    float xs = (res + 1.0f) * 127.5f;      // (nlevels-1)/2
    float f = floorf(xs);
    float frac = xs - f;
    int i0 = (int)f;
    int j0 = (i0 < 0) ? i0 + NLEV : i0;    // JAX negative-index wrap
    if ((unsigned)j0 < (unsigned)NLEV) atomicAdd(&h[j0], 1.0f - frac);
    int i1 = i0 + 1;
    int j1 = (i1 < 0) ? i1 + NLEV : i1;
    if ((unsigned)j1 < (unsigned)NLEV) atomicAdd(&h[j1], frac);
}

__global__ void zero_hist() {
    int i = blockIdx.x * 256 + threadIdx.x;
    if (i < NHIST) g_hist[i] = 0.0f;
}

__global__ __launch_bounds__(512) void hist_kernel(const float* __restrict__ x,
                                                   const float* __restrict__ params) {
    // per-wave sub-histograms: 8 waves x 3 channels x 256 bins = 24 KiB
    __shared__ float lh[8][NC][NLEV];
    const int tid = threadIdx.x;
    const int b = blockIdx.x;
    const int r0 = blockIdx.y * RPB;
    const int wv = tid >> 6;
    const int lane = tid & 63;
    const int col = tid;   // 0..511, one column per thread

    float* lp = &lh[0][0][0];
    for (int i = tid; i < 8 * NC * NLEV; i += 512) lp[i] = 0.0f;
    __syncthreads();

    float p[12];
#pragma unroll
    for (int i = 0; i < 12; ++i) p[i] = params[i];

    // north / northwest carried in registers across rows.
    F3 n = {0.f, 0.f, 0.f}, nw = {0.f, 0.f, 0.f};
    if (r0 > 0) {
        n = transform(x, p, b, r0 - 1, col);
        nw.r = __shfl_up(n.r, 1);
        nw.g = __shfl_up(n.g, 1);
        nw.b = __shfl_up(n.b, 1);
        if (lane == 0) {
            if (col > 0) nw = transform(x, p, b, r0 - 1, col - 1);
            else nw = F3{0.f, 0.f, 0.f};
        }
    }

    float* h0 = &lh[wv][0][0];
    float* h1 = &lh[wv][1][0];
    float* h2 = &lh[wv][2][0];

    for (int h = r0; h < r0 + RPB; ++h) {
        F3 cur = transform(x, p, b, h, col);
        // west via cross-lane shuffle; lane 0 recomputes (prev wave's column)
        F3 wst;
        wst.r = __shfl_up(cur.r, 1);
        wst.g = __shfl_up(cur.g, 1);
        wst.b = __shfl_up(cur.b, 1);
        if (lane == 0) {
            if (col > 0) wst = transform(x, p, b, h, col - 1);
            else wst = F3{0.f, 0.f, 0.f};
        }
        accum(cur.r, n.r, wst.r, nw.r, h0);
        accum(cur.g, n.g, wst.g, nw.g, h1);
        accum(cur.b, n.b, wst.b, nw.b, h2);
        n = cur;
        nw = wst;
    }
    __syncthreads();

    // flush: sum the 8 sub-histograms, one global atomic per bin
    for (int i = tid; i < NC * NLEV; i += 512) {
        int c = i >> 8;
        int bin = i & 255;
        float s = 0.0f;
#pragma unroll
        for (int w2 = 0; w2 < 8; ++w2) s += lh[w2][c][bin];
        atomicAdd(&g_hist[(b * NC + c) * NLEV + bin], s);
    }
}

__global__ __launch_bounds__(1024) void entropy_kernel(float* __restrict__ out) {
    const float inv_hw = 1.0f / (float)(IMG_H * IMG_W);
    float acc = 0.0f;
    for (int i = threadIdx.x; i < NHIST; i += 1024) {
        float pr = g_hist[i] * inv_hw;
        if (pr > 0.0f) acc -= pr * log2f(pr);
    }
#pragma unroll
    for (int o = 32; o > 0; o >>= 1) acc += __shfl_down(acc, o);
    __shared__ float red[16];
    int wv = threadIdx.x >> 6;
    int lane = threadIdx.x & 63;
    if (lane == 0) red[wv] = acc;
    __syncthreads();
    if (threadIdx.x == 0) {
        float t = 0.0f;
#pragma unroll
        for (int i = 0; i < 16; ++i) t += red[i];
        out[0] = t * (1.0f / (float)(NB * NC) / 8.0f);  // mean over 96 rows, /nbits
    }
}

extern "C" void kernel_launch(void* const* d_in, const int* in_sizes, int n_in,
                              void* d_out, int out_size, void* d_ws, size_t ws_size,
                              hipStream_t stream) {
    const float* x = (const float*)d_in[0];
    const float* params = (const float*)d_in[1];
    float* out = (float*)d_out;

    zero_hist<<<(NHIST + 255) / 256, 256, 0, stream>>>();
    dim3 grid(NB, IMG_H / RPB);   // 32 x 32
    hist_kernel<<<grid, 512, 0, stream>>>(x, params);
    entropy_kernel<<<1, 1024, 0, stream>>>(out);
}

// Round 5
// 249.743 us; speedup vs baseline: 1.0629x; 1.0017x over previous
//
#include <hip/hip_runtime.h>

#define IMG_H 512
#define IMG_W 512
#define RPB 16            // rows per block
#define NLEV 256
#define NB 32             // batch
#define NC 3              // channels
#define NHIST (NB * NC * NLEV)   // 24576 floats

__device__ float g_hist[NHIST];

struct F3 { float r, g, b; };

// fmodf(v+1, 2) - 1, branch-free. Exact: a*0.5 exact, trunc exact,
// a - 2*t is a multiple of ulp(a) with smaller magnitude -> exact.
__device__ __forceinline__ float wrap1(float v) {
    float a = v + 1.0f;
    return a - 2.0f * truncf(0.5f * a) - 1.0f;
}

// Color transform + wrap for pixel (b,h,w). 3 global loads.
__device__ __forceinline__ F3 transform(const float* __restrict__ x,
                                        const float* __restrict__ p,
                                        int b, int h, int w) {
    int base = ((b * 3) * IMG_H + h) * IMG_W + w;
    float r0 = x[base];
    float g0 = x[base + IMG_H * IMG_W];
    float b0 = x[base + 2 * IMG_H * IMG_W];
    float r1 = r0 + (p[0] * g0 + p[1] * b0);
    float g1 = g0 + (p[2] * r1 + p[3] * b0);
    float b1 = b0 + (p[4] * r1 + p[5] * g1);
    float r2 = r1 + (p[6] * g1 + p[7] * b1);
    float g2 = g1 + (p[8] * r2 + p[9] * b1);
    float b2 = b1 + (p[10] * r2 + p[11] * g2);
    return F3{wrap1(r2), wrap1(g2), wrap1(b2)};
}

// Residual -> 2 histogram adds. JAX semantics: negative indices wrap (+256)
// BEFORE the bounds check; only then are OOB indices dropped (mode='drop').
// unsafeAtomicAdd emits native ds_add_f32 (atomicAdd(float*) without
// -munsafe-fp-atomics lowers to a CAS retry loop).
__device__ __forceinline__ void accum(float y, float n, float w, float nw,
                                      float* __restrict__ h) {
    float lo = fminf(n, w), hi = fmaxf(n, w);
    float pred = fminf(fmaxf(n + w - nw, lo), hi);
    float res = y - pred;
    float xs = (res + 1.0f) * 127.5f;      // (nlevels-1)/2
    float f = floorf(xs);
    float frac = xs - f;
    int i0 = (int)f;
    int j0 = (i0 < 0) ? i0 + NLEV : i0;    // JAX negative-index wrap
    if ((unsigned)j0 < (unsigned)NLEV) unsafeAtomicAdd(&h[j0], 1.0f - frac);
    int i1 = i0 + 1;
    int j1 = (i1 < 0) ? i1 + NLEV : i1;
    if ((unsigned)j1 < (unsigned)NLEV) unsafeAtomicAdd(&h[j1], frac);
}

__global__ void zero_hist() {
    int i = blockIdx.x * 256 + threadIdx.x;
    if (i < NHIST) g_hist[i] = 0.0f;
}

__global__ __launch_bounds__(512) void hist_kernel(const float* __restrict__ x,
                                                   const float* __restrict__ params) {
    // per-wave sub-histograms: 8 waves x 3 channels x 256 bins = 24 KiB
    __shared__ float lh[8][NC][NLEV];
    const int tid = threadIdx.x;
    const int b = blockIdx.x;
    const int r0 = blockIdx.y * RPB;
    const int wv = tid >> 6;
    const int lane = tid & 63;
    const int col = tid;   // 0..511, one column per thread

    float* lp = &lh[0][0][0];
    for (int i = tid; i < 8 * NC * NLEV; i += 512) lp[i] = 0.0f;
    __syncthreads();

    float p[12];
#pragma unroll
    for (int i = 0; i < 12; ++i) p[i] = params[i];

    // north / northwest carried in registers across rows.
    F3 n = {0.f, 0.f, 0.f}, nw = {0.f, 0.f, 0.f};
    if (r0 > 0) {
        n = transform(x, p, b, r0 - 1, col);
        nw.r = __shfl_up(n.r, 1);
        nw.g = __shfl_up(n.g, 1);
        nw.b = __shfl_up(n.b, 1);
        if (lane == 0) {
            if (col > 0) nw = transform(x, p, b, r0 - 1, col - 1);
            else nw = F3{0.f, 0.f, 0.f};
        }
    }

    float* h0 = &lh[wv][0][0];
    float* h1 = &lh[wv][1][0];
    float* h2 = &lh[wv][2][0];

    for (int h = r0; h < r0 + RPB; ++h) {
        F3 cur = transform(x, p, b, h, col);
        // west via cross-lane shuffle; lane 0 recomputes (prev wave's column)
        F3 wst;
        wst.r = __shfl_up(cur.r, 1);
        wst.g = __shfl_up(cur.g, 1);
        wst.b = __shfl_up(cur.b, 1);
        if (lane == 0) {
            if (col > 0) wst = transform(x, p, b, h, col - 1);
            else wst = F3{0.f, 0.f, 0.f};
        }
        accum(cur.r, n.r, wst.r, nw.r, h0);
        accum(cur.g, n.g, wst.g, nw.g, h1);
        accum(cur.b, n.b, wst.b, nw.b, h2);
        n = cur;
        nw = wst;
    }
    __syncthreads();

    // flush: sum the 8 sub-histograms, one native global atomic per bin
    for (int i = tid; i < NC * NLEV; i += 512) {
        int c = i >> 8;
        int bin = i & 255;
        float s = 0.0f;
#pragma unroll
        for (int w2 = 0; w2 < 8; ++w2) s += lh[w2][c][bin];
        unsafeAtomicAdd(&g_hist[(b * NC + c) * NLEV + bin], s);
    }
}

__global__ __launch_bounds__(1024) void entropy_kernel(float* __restrict__ out) {
    const float inv_hw = 1.0f / (float)(IMG_H * IMG_W);
    float acc = 0.0f;
    for (int i = threadIdx.x; i < NHIST; i += 1024) {
        float pr = g_hist[i] * inv_hw;
        if (pr > 0.0f) acc -= pr * log2f(pr);
    }
#pragma unroll
    for (int o = 32; o > 0; o >>= 1) acc += __shfl_down(acc, o);
    __shared__ float red[16];
    int wv = threadIdx.x >> 6;
    int lane = threadIdx.x & 63;
    if (lane == 0) red[wv] = acc;
    __syncthreads();
    if (threadIdx.x == 0) {
        float t = 0.0f;
#pragma unroll
        for (int i = 0; i < 16; ++i) t += red[i];
        out[0] = t * (1.0f / (float)(NB * NC) / 8.0f);  // mean over 96 rows, /nbits
    }
}

extern "C" void kernel_launch(void* const* d_in, const int* in_sizes, int n_in,
                              void* d_out, int out_size, void* d_ws, size_t ws_size,
                              hipStream_t stream) {
    const float* x = (const float*)d_in[0];
    const float* params = (const float*)d_in[1];
    float* out = (float*)d_out;

    zero_hist<<<(NHIST + 255) / 256, 256, 0, stream>>>();
    dim3 grid(NB, IMG_H / RPB);   // 32 x 32
    hist_kernel<<<grid, 512, 0, stream>>>(x, params);
    entropy_kernel<<<1, 1024, 0, stream>>>(out);
}